// Round 13
// baseline (21.386 us; speedup 1.0000x reference)
//
#include <hip/hip_runtime.h>

// sites [4096,128] f32, consensus [512,128] f32
// out = softmax(-L1dist, axis=-1) -> [4096,512] f32
#define N_SITES 4096
#define M_CONS  512
#define DIM     128
#define RPB     8         // site rows per block
#define CH      16        // dims per chunk
#define NCH     8         // chunks

// Single fused kernel, R12 structure with WAVE-PRIVATE double buffers:
// zero barriers in the K-loop.
// 512 blocks x 512 threads, 64 KB LDS -> 2 blocks/CU = 4 waves/SIMD.
// Wave wv owns cons columns [wv*64, wv*64+64); lane ln owns col wv*64+ln
// (cv[16] in VGPRs; sites block-uniform -> s_load -> SGPR operand; inner
// loop pure VALU - validated R9/R11/R12).
// Per wave, per chunk h: s_waitcnt vmcnt(4) (in-order retirement => group h
// landed, group h+1 still in flight) -> extract 4 x ds_read_b128 -> compute
// 8x16 dims -> s_waitcnt lgkmcnt(0) (extract done, buffer safe to overwrite)
// -> issue 4 global_load_lds for chunk h+2 into the just-freed buffer.
// Waves free-run; the only __syncthreads is before the softmax overlay.
// Swizzle (#21 both-sides): stored slot q of local col c holds global quad
// q ^ ((c>>1)&3); extract reads slot g ^ ((ln>>1)&3). LDS dest stays linear
// (wave-uniform base + lane*16) as global_load_lds requires.
__global__ __launch_bounds__(512, 1) void fused_kernel(const float* __restrict__ sites,
                                                       const float* __restrict__ cons,
                                                       float* __restrict__ out) {
    __shared__ __align__(16) float lds[16384];   // 64 KB = 8 waves x 2 x 4 KB

    const int tid = threadIdx.x;
    const int bid = blockIdx.x;
    const int r0  = bid * RPB;
    const int wv  = tid >> 6;
    const int ln  = tid & 63;

    float* wbase = &lds[wv * 2048];              // this wave's 8 KB slice

    // ---- DMA one chunk into wave-private buffer b (4 calls, lane-linear dest)
    auto issue = [&](int h, int b) {
        float* dst = wbase + b * 1024;
#pragma unroll
        for (int it = 0; it < 4; it++) {
            const int f = it * 64 + ln;          // slot 0..255
            const int c = f >> 2, q = f & 3;     // local col, quad slot
            const float* gsrc = cons + (size_t)(wv * 64 + c) * DIM + h * CH
                                     + ((q ^ ((c >> 1) & 3)) << 2);
            __builtin_amdgcn_global_load_lds(
                (const __attribute__((address_space(1))) void*)gsrc,
                (__attribute__((address_space(3))) void*)&dst[f * 4], 16, 0, 0);
        }
    };

    // ---- prologue: fill both buffers (chunks 0 and 1)
    issue(0, 0);
    issue(1, 1);

    float d[RPB];
#pragma unroll
    for (int i = 0; i < RPB; i++) d[i] = 0.f;

    const float* srow = sites + (size_t)r0 * DIM;
    const int key = (ln >> 1) & 3;

#pragma unroll
    for (int h = 0; h < NCH; h++) {
        // wait for group h (4 oldest); group h+1 (4 newer) may stay in flight
        if (h < NCH - 1) {
            asm volatile("s_waitcnt vmcnt(4)" ::: "memory");
        } else {
            asm volatile("s_waitcnt vmcnt(0)" ::: "memory");
        }

        // ---- extract my column's 16 dims from my wave's buffer
        const float* B = wbase + (h & 1) * 1024;
        float cv[CH];
#pragma unroll
        for (int g = 0; g < 4; g++) {
            float4 v = *(const float4*)&B[ln * 16 + ((g ^ key) << 2)];
            cv[4*g+0] = v.x; cv[4*g+1] = v.y; cv[4*g+2] = v.z; cv[4*g+3] = v.w;
        }

        // ---- pure-VALU accumulation: 8 rows x 16 dims (srow -> SGPR)
#pragma unroll
        for (int rr = 0; rr < RPB; rr++) {
#pragma unroll
            for (int k = 0; k < CH; k++)
                d[rr] += fabsf(srow[rr * DIM + h * CH + k] - cv[k]);
        }

        // ---- refill the just-read buffer with chunk h+2
        if (h < NCH - 2) {
            asm volatile("s_waitcnt lgkmcnt(0)" ::: "memory");  // extract done
            issue(h + 2, h & 1);
        }
    }

    // ---- block-local softmax: dmat[8][512] overlay (16 KB of LDS)
    __syncthreads();                             // all waves done with buffers
#pragma unroll
    for (int rr = 0; rr < RPB; rr++)
        lds[rr * 512 + tid] = d[rr];             // consecutive lanes: free
    __syncthreads();

    {
        const float* p = &lds[wv * 512 + ln * 8];   // wave wv reduces row wv
        float4 a = *(const float4*)(p);
        float4 b = *(const float4*)(p + 4);
        float m = fminf(fminf(fminf(a.x, a.y), fminf(a.z, a.w)),
                        fminf(fminf(b.x, b.y), fminf(b.z, b.w)));
#pragma unroll
        for (int off = 32; off > 0; off >>= 1) m = fminf(m, __shfl_xor(m, off));
        float s = ((__expf(m - a.x) + __expf(m - a.y)) + (__expf(m - a.z) + __expf(m - a.w)))
                + ((__expf(m - b.x) + __expf(m - b.y)) + (__expf(m - b.z) + __expf(m - b.w)));
#pragma unroll
        for (int off = 32; off > 0; off >>= 1) s += __shfl_xor(s, off);
        if (ln == 0) {
            lds[4096 + wv] = m;                  // row min
            lds[4104 + wv] = 1.f / s;            // row inv-sum
        }
    }
    __syncthreads();

    // ---- final: exp(mn - d) * inv from registers, coalesced 2 KB stores
#pragma unroll
    for (int rr = 0; rr < RPB; rr++) {
        float mn  = lds[4096 + rr];              // broadcast (same address)
        float inv = lds[4104 + rr];
        out[(size_t)(r0 + rr) * M_CONS + tid] = __expf(mn - d[rr]) * inv;
    }
}

extern "C" void kernel_launch(void* const* d_in, const int* in_sizes, int n_in,
                              void* d_out, int out_size, void* d_ws, size_t ws_size,
                              hipStream_t stream) {
    const float* sites = (const float*)d_in[0];
    const float* cons  = (const float*)d_in[1];
    float* out = (float*)d_out;

    fused_kernel<<<N_SITES / RPB, 512, 0, stream>>>(sites, cons, out);  // 512 blocks
}